// Round 4
// baseline (4203.102 us; speedup 1.0000x reference)
//
#include <hip/hip_runtime.h>

// RecNet: xh = x@Wx2h.T + b_x2h  (once);  128x: h = relu(xh + h@Wh2h.T + b_h2h);
//         out = h@Wh2y.T + b_h2y.
// Strategy: 32 independent row-groups (16 batch rows) x 8 col-WGs (64 hidden cols).
// Wh2h register-resident as bf16 hi/lo MFMA fragments (3-product fp32 emulation).
// Per-step h exchange through MALL in MFMA-fragment order + per-group atomic
// counter, with agent-scope release/acquire fences (buffer_wbl2/buffer_inv sc1)
// so correctness does NOT depend on WG->XCD mapping (G16).
// 102KB dynamic LDS forces 1 WG/CU -> all 256 WGs co-resident (spin-safe).

typedef __attribute__((ext_vector_type(8))) short short8;
typedef __attribute__((ext_vector_type(4))) float f32x4;
typedef __attribute__((ext_vector_type(2))) float f32x2;

#define LDS_BYTES 102400
#define XS_OFF 0       // x stage   [16][132] f32 = 8448 B
#define XB_OFF 8448    // xb        [16][68]  f32 = 4352 B
#define RED_OFF 12800  // reduction [2][16][36] f32 = 4608 B
#define HF_OFF 0       // epilogue h_f32 [16][520] f32 = 33280 B
#define WL_OFF 33280   // epilogue Wlds  [32][522] f32 = 66816 B (end 100096)

#define HBUF_BYTES (1u << 20)  // one fragment-order h buffer: 32 grp *16 ch *64 ln *32B
#define CTR_OFF (2u << 20)

__device__ __forceinline__ unsigned short f2bf(float f) {
  unsigned u = __builtin_bit_cast(unsigned, f);
  u += 0x7FFFu + ((u >> 16) & 1u);  // RNE (inputs finite)
  return (unsigned short)(u >> 16);
}
__device__ __forceinline__ float bf2f(unsigned short h) {
  unsigned u = ((unsigned)h) << 16;
  return __builtin_bit_cast(float, u);
}

extern "C" __global__ void __launch_bounds__(256, 1)
recnet_kernel(const float* __restrict__ x, const float* __restrict__ Wx2h,
              const float* __restrict__ bx2h, const float* __restrict__ Wh2h,
              const float* __restrict__ bh2h, const float* __restrict__ Wh2y,
              const float* __restrict__ bh2y, float* __restrict__ out,
              char* __restrict__ ws) {
  extern __shared__ char smem[];
  const int tid = threadIdx.x;
  const int l   = tid & 63;
  const int wv  = tid >> 6;
  const int ct  = wv & 1;   // col-half of this WG's 64 cols
  const int kh  = wv >> 1;  // K-half (0: k<256 + xb, 1: k>=256)
  const int bid = blockIdx.x;
  const int g   = bid & 31;  // row-group; bids {g,g+32,..} likely share XCD (perf only)
  const int cb  = bid >> 5;  // col-block 0..7
  const int rowbase = g << 4;
  const int colbase = cb << 6;
  const int l15 = l & 15;
  const int lq  = l >> 4;

  char* hbuf0 = ws;
  char* hbuf1 = ws + HBUF_BYTES;
  int* ctr = (int*)(ws + CTR_OFF);

  // ---- Wh2h fragment preload: bf16 hi/lo, register resident (128 VGPR) ----
  // B-frag: lane holds col=l&15, k = kb0 + chunk*32 + (l>>4)*8 + e.
  // (Same k-placement function used for A in store_h -> result invariant to
  //  the hardware's intra-lane k permutation, since A/B layouts are mirror.)
  short8 Whi[8][2], Wlo[8][2];
  {
    const int kb0 = (kh << 8) + (lq << 3);
#pragma unroll
    for (int c = 0; c < 8; ++c) {
#pragma unroll
      for (int t2 = 0; t2 < 2; ++t2) {
        const int col = colbase + (ct << 5) + (t2 << 4) + l15;
        const float* p = Wh2h + (size_t)col * 512 + kb0 + c * 32;
        f32x4 w0 = *(const f32x4*)p;
        f32x4 w1 = *(const f32x4*)(p + 4);
        short8 hi8, lo8;
#pragma unroll
        for (int e = 0; e < 4; ++e) {
          unsigned short h = f2bf(w0[e]);
          hi8[e] = (short)h;
          lo8[e] = (short)f2bf(w0[e] - bf2f(h));
        }
#pragma unroll
        for (int e = 0; e < 4; ++e) {
          unsigned short h = f2bf(w1[e]);
          hi8[4 + e] = (short)h;
          lo8[4 + e] = (short)f2bf(w1[e] - bf2f(h));
        }
        Whi[c][t2] = hi8;
        Wlo[c][t2] = lo8;
      }
    }
  }

  // ---- xb = x@Wx2h.T + b_x2h + b_h2h  (fp32 VALU, once) ----
  {
    const int r = tid >> 4, ci = tid & 15;
    float* xs = (float*)(smem + XS_OFF);
    const float* xp = x + (size_t)(rowbase + r) * 128 + ci * 8;
    f32x4 v0 = *(const f32x4*)xp;
    f32x4 v1 = *(const f32x4*)(xp + 4);
    *(f32x4*)&xs[r * 132 + ci * 8] = v0;
    *(f32x4*)&xs[r * 132 + ci * 8 + 4] = v1;
  }
  __syncthreads();
  {
    const int r = tid >> 4, c4 = (tid & 15) << 2;
    const int jg = colbase + c4;
    f32x4 acc = *(const f32x4*)&bx2h[jg];
    acc += *(const f32x4*)&bh2h[jg];
    const float* xs = (const float*)(smem + XS_OFF);
#pragma unroll 2
    for (int k = 0; k < 128; k += 4) {
      f32x4 xv = *(const f32x4*)&xs[r * 132 + k];
#pragma unroll
      for (int jj = 0; jj < 4; ++jj) {
        f32x4 wvv = *(const f32x4*)(Wx2h + (size_t)(jg + jj) * 128 + k);
        acc[jj] += xv[0] * wvv[0] + xv[1] * wvv[1] + xv[2] * wvv[2] + xv[3] * wvv[3];
      }
    }
    float* xbl = (float*)(smem + XB_OFF);
    *(f32x4*)&xbl[r * 68 + c4] = acc;
  }
  __syncthreads();

  // kh==0 waves keep xb as C-init fragments (C layout: col=l&15, row=lq*4+j)
  f32x4 xbf0 = {0, 0, 0, 0}, xbf1 = {0, 0, 0, 0};
  if (kh == 0) {
    const float* xbl = (const float*)(smem + XB_OFF);
#pragma unroll
    for (int j = 0; j < 4; ++j) {
      xbf0[j] = xbl[(lq * 4 + j) * 68 + (ct << 5) + l15];
      xbf1[j] = xbl[(lq * 4 + j) * 68 + (ct << 5) + 16 + l15];
    }
  }

  // store h values (relu applied) into fragment-order buffer, hi/lo bf16
  auto store_h = [&](char* buf, f32x4 s0, f32x4 s1) {
    const int cg = (cb << 1) + ct;  // global k-chunk this wave's cols map to
#pragma unroll
    for (int t2 = 0; t2 < 2; ++t2) {
      f32x4 sv = t2 ? s1 : s0;
      const int koff = (t2 << 4) + l15;            // 0..31 within chunk
      const int lcb = ((koff >> 3) << 4);          // consumer lane base
#pragma unroll
      for (int j = 0; j < 4; ++j) {
        float v = sv[j];
        v = v > 0.f ? v : 0.f;
        unsigned short hi = f2bf(v);
        unsigned short lo = f2bf(v - bf2f(hi));
        const int row = (lq << 2) + j;
        char* p = buf + (((size_t)(g * 16 + cg) * 64 + lcb + row) << 5) +
                  ((l & 7) << 1);
        *(unsigned short*)p = hi;
        *(unsigned short*)(p + 16) = lo;
      }
    }
  };

  // Agent-scope message passing: correct under ANY WG->XCD mapping.
  auto sync_step = [&](int t) {
    // release: s_waitcnt vmcnt(0) + buffer_wbl2 sc1 -> h stores reach MALL
    __builtin_amdgcn_fence(__ATOMIC_RELEASE, "agent");
    __syncthreads();  // all waves' fences complete before the signal
    if (tid == 0) {
      atomicAdd(ctr + g, 1);  // device-scope signal
      const int target = 8 * (t + 1);
      while (__hip_atomic_load(ctr + g, __ATOMIC_RELAXED,
                               __HIP_MEMORY_SCOPE_AGENT) < target)
        __builtin_amdgcn_s_sleep(1);
    }
    __syncthreads();
    // acquire: buffer_inv sc1 -> next h loads refill from MALL (no stale L2/L1)
    __builtin_amdgcn_fence(__ATOMIC_ACQUIRE, "agent");
  };

  // ---- t=0: h = relu(xb) ----
  if (kh == 0) store_h(hbuf0, xbf0, xbf1);
  sync_step(0);

  // ---- 127 recurrence steps ----
  for (int t = 1; t < 128; ++t) {
    const char* hb = ((t & 1) ? hbuf0 : hbuf1) +
                     ((size_t)(g * 16 + kh * 8) << 11) + (l << 5);
    f32x4 a0, a1, b0, b1;
    if (kh == 0) {
      a0 = xbf0; a1 = xbf1;
    } else {
      a0 = (f32x4){0, 0, 0, 0}; a1 = a0;
    }
    b0 = (f32x4){0, 0, 0, 0}; b1 = b0;
#pragma unroll
    for (int c = 0; c < 8; ++c) {
      short8 ahi = *(const short8*)(hb + (c << 11));
      short8 alo = *(const short8*)(hb + (c << 11) + 16);
      if ((c & 1) == 0) {
        a0 = __builtin_amdgcn_mfma_f32_16x16x32_bf16(ahi, Whi[c][0], a0, 0, 0, 0);
        a0 = __builtin_amdgcn_mfma_f32_16x16x32_bf16(alo, Whi[c][0], a0, 0, 0, 0);
        a0 = __builtin_amdgcn_mfma_f32_16x16x32_bf16(ahi, Wlo[c][0], a0, 0, 0, 0);
        a1 = __builtin_amdgcn_mfma_f32_16x16x32_bf16(ahi, Whi[c][1], a1, 0, 0, 0);
        a1 = __builtin_amdgcn_mfma_f32_16x16x32_bf16(alo, Whi[c][1], a1, 0, 0, 0);
        a1 = __builtin_amdgcn_mfma_f32_16x16x32_bf16(ahi, Wlo[c][1], a1, 0, 0, 0);
      } else {
        b0 = __builtin_amdgcn_mfma_f32_16x16x32_bf16(ahi, Whi[c][0], b0, 0, 0, 0);
        b0 = __builtin_amdgcn_mfma_f32_16x16x32_bf16(alo, Whi[c][0], b0, 0, 0, 0);
        b0 = __builtin_amdgcn_mfma_f32_16x16x32_bf16(ahi, Wlo[c][0], b0, 0, 0, 0);
        b1 = __builtin_amdgcn_mfma_f32_16x16x32_bf16(ahi, Whi[c][1], b1, 0, 0, 0);
        b1 = __builtin_amdgcn_mfma_f32_16x16x32_bf16(alo, Whi[c][1], b1, 0, 0, 0);
        b1 = __builtin_amdgcn_mfma_f32_16x16x32_bf16(ahi, Wlo[c][1], b1, 0, 0, 0);
      }
    }
    f32x4 s0 = a0 + b0, s1 = a1 + b1;
    float* red = (float*)(smem + RED_OFF);
    if (kh == 1) {  // write K-half partials for the kh==0 partner wave
#pragma unroll
      for (int t2 = 0; t2 < 2; ++t2)
#pragma unroll
        for (int j = 0; j < 4; ++j)
          red[(ct * 16 + lq * 4 + j) * 36 + t2 * 16 + l15] = t2 ? s1[j] : s0[j];
    }
    __syncthreads();
    if (kh == 0) {
#pragma unroll
      for (int t2 = 0; t2 < 2; ++t2)
#pragma unroll
        for (int j = 0; j < 4; ++j) {
          float rv = red[(ct * 16 + lq * 4 + j) * 36 + t2 * 16 + l15];
          if (t2) s1[j] += rv; else s0[j] += rv;
        }
      store_h((t & 1) ? hbuf1 : hbuf0, s0, s1);
    }
    sync_step(t);
  }

  // ---- epilogue: out = h@Wh2y.T + b_h2y (fp32 VALU via LDS) ----
  {  // reconstruct final h (buf1, fragment order) -> h_f32[16][520]
    const int r = tid >> 4, cgi = tid & 15;
    float* hf = (float*)(smem + HF_OFF);
    const char* hb = hbuf1 + ((size_t)(g * 16 + cgi) << 11);
#pragma unroll
    for (int lg = 0; lg < 4; ++lg) {
      const char* p = hb + ((lg * 16 + r) << 5);
      short8 hi8 = *(const short8*)p;
      short8 lo8 = *(const short8*)(p + 16);
      f32x4 v0, v1;
#pragma unroll
      for (int e = 0; e < 4; ++e)
        v0[e] = bf2f((unsigned short)hi8[e]) + bf2f((unsigned short)lo8[e]);
#pragma unroll
      for (int e = 0; e < 4; ++e)
        v1[e] = bf2f((unsigned short)hi8[4 + e]) + bf2f((unsigned short)lo8[4 + e]);
      *(f32x4*)&hf[r * 520 + cgi * 32 + lg * 8] = v0;
      *(f32x4*)&hf[r * 520 + cgi * 32 + lg * 8 + 4] = v1;
    }
  }
  {  // stage Wh2y slice [32][522]
    float* wl = (float*)(smem + WL_OFF);
    const int wr = tid >> 3, seg = tid & 7;
    const int ocb = cb << 5;
    const float* wp = Wh2y + (size_t)(ocb + wr) * 512;
#pragma unroll 8
    for (int i = 0; i < 32; ++i) {
      const int c = (seg + i * 8) << 1;
      *(f32x2*)&wl[wr * 522 + c] = *(const f32x2*)&wp[c];
    }
  }
  __syncthreads();
  {
    const int r = tid >> 4, c2 = (tid & 15) << 1;
    const int ocb = cb << 5;
    const float* hf = (const float*)(smem + HF_OFF);
    const float* wl = (const float*)(smem + WL_OFF);
    float acc0 = 0.f, acc1 = 0.f;
#pragma unroll 8
    for (int k = 0; k < 512; k += 2) {
      f32x2 hv = *(const f32x2*)&hf[r * 520 + k];
      f32x2 w0 = *(const f32x2*)&wl[c2 * 522 + k];
      f32x2 w1 = *(const f32x2*)&wl[(c2 + 1) * 522 + k];
      acc0 += hv[0] * w0[0] + hv[1] * w0[1];
      acc1 += hv[0] * w1[0] + hv[1] * w1[1];
    }
    acc0 += bh2y[ocb + c2];
    acc1 += bh2y[ocb + c2 + 1];
    f32x2 o; o[0] = acc0; o[1] = acc1;
    *(f32x2*)&out[(size_t)(rowbase + r) * 256 + ocb + c2] = o;
  }
}

extern "C" void kernel_launch(void* const* d_in, const int* in_sizes, int n_in,
                              void* d_out, int out_size, void* d_ws,
                              size_t ws_size, hipStream_t stream) {
  const float* x    = (const float*)d_in[0];
  const float* Wx2h = (const float*)d_in[1];
  const float* bx2h = (const float*)d_in[2];
  const float* Wh2h = (const float*)d_in[3];
  const float* bh2h = (const float*)d_in[4];
  const float* Wh2y = (const float*)d_in[5];
  const float* bh2y = (const float*)d_in[6];
  // zero the 32 per-group arrival counters (ws is re-poisoned each call)
  (void)hipMemsetAsync((char*)d_ws + CTR_OFF, 0, 256, stream);
  (void)hipFuncSetAttribute((const void*)recnet_kernel,
                            hipFuncAttributeMaxDynamicSharedMemorySize,
                            LDS_BYTES);
  recnet_kernel<<<dim3(256), dim3(256), LDS_BYTES, stream>>>(
      x, Wx2h, bx2h, Wh2h, bh2h, Wh2y, bh2y, (float*)d_out, (char*)d_ws);
}

// Round 5
// 527.791 us; speedup vs baseline: 7.9636x; 7.9636x over previous
//
#include <hip/hip_runtime.h>

// RecNet: xh = x@Wx2h.T + b_x2h  (once);  128x: h = relu(xh + h@Wh2h.T + b_h2h);
//         out = h@Wh2y.T + b_h2y.
// Strategy: 32 independent row-groups (16 batch rows) x 8 col-WGs (64 hidden cols).
// Wh2h register-resident as bf16 hi/lo MFMA fragments (3-product fp32 emulation).
// R4 lesson: agent fences (buffer_wbl2/buffer_inv, full-L2 walks per wave per
// step) cost ~33us/step -> REMOVED. h now exchanged via per-access coherent
// relaxed agent-scope dword atomics (hi|lo bf16 packed), which bypass the
// non-coherent L1/L2 and hit the MALL directly. Ordering: __syncthreads drains
// vmcnt (stores acked at MALL) before the tid0 signal; consumer loads are
// MALL-direct so no invalidate is needed. Mapping-independent (G16-safe).
// Counters padded to 256B/group (R4: 4B apart = one contended MALL line).
// 102KB dynamic LDS forces 1 WG/CU -> all 256 WGs co-resident (spin-safe).

typedef __attribute__((ext_vector_type(8))) short short8;
typedef __attribute__((ext_vector_type(4))) float f32x4;
typedef __attribute__((ext_vector_type(2))) float f32x2;

#define LDS_BYTES 102400
#define XS_OFF 0       // x stage   [16][132] f32 = 8448 B
#define XB_OFF 8448    // xb        [16][68]  f32 = 4352 B
#define RED_OFF 12800  // reduction [2][16][36] f32 = 4608 B
#define HF_OFF 0       // epilogue h_f32 [16][520] f32 = 33280 B
#define WL_OFF 33280   // epilogue Wlds  [32][522] f32 = 66816 B (end 100096)

// h buffer: 32 grp * 16 chunks * 512 dwords (dword = hi|lo<<16 bf16 of one
// elem; within a chunk, dword index = e*64 + consumer_lane -> 256B coalesced
// loads per (e) across lanes). 1 MB per buffer.
#define HBUF_BYTES (1u << 20)
#define CTR_OFF (2u << 20)
#define CTR_STRIDE 64  // ints; 256B per group counter line

__device__ __forceinline__ unsigned short f2bf(float f) {
  unsigned u = __builtin_bit_cast(unsigned, f);
  u += 0x7FFFu + ((u >> 16) & 1u);  // RNE (inputs finite)
  return (unsigned short)(u >> 16);
}
__device__ __forceinline__ float bf2f(unsigned short h) {
  unsigned u = ((unsigned)h) << 16;
  return __builtin_bit_cast(float, u);
}

extern "C" __global__ void __launch_bounds__(256, 1)
recnet_kernel(const float* __restrict__ x, const float* __restrict__ Wx2h,
              const float* __restrict__ bx2h, const float* __restrict__ Wh2h,
              const float* __restrict__ bh2h, const float* __restrict__ Wh2y,
              const float* __restrict__ bh2y, float* __restrict__ out,
              char* __restrict__ ws) {
  extern __shared__ char smem[];
  const int tid = threadIdx.x;
  const int l   = tid & 63;
  const int wv  = tid >> 6;
  const int ct  = wv & 1;   // col-half of this WG's 64 cols
  const int kh  = wv >> 1;  // K-half (0: k<256 + xb, 1: k>=256)
  const int bid = blockIdx.x;
  const int g   = bid & 31;  // row-group; bids {g,g+32,..} likely share XCD (perf only)
  const int cb  = bid >> 5;  // col-block 0..7
  const int rowbase = g << 4;
  const int colbase = cb << 6;
  const int l15 = l & 15;
  const int lq  = l >> 4;

  unsigned* hbuf0 = (unsigned*)ws;
  unsigned* hbuf1 = (unsigned*)(ws + HBUF_BYTES);
  int* ctr_g = (int*)(ws + CTR_OFF) + g * CTR_STRIDE;

  // ---- Wh2h fragment preload: bf16 hi/lo, register resident (128 VGPR) ----
  // B-frag: lane holds col=l&15, k = kb0 + chunk*32 + (l>>4)*8 + e.
  // (Same k-placement function used for A in store_h -> result invariant to
  //  any intra-lane k permutation, since A/B layouts are mirror.)
  short8 Whi[8][2], Wlo[8][2];
  {
    const int kb0 = (kh << 8) + (lq << 3);
#pragma unroll
    for (int c = 0; c < 8; ++c) {
#pragma unroll
      for (int t2 = 0; t2 < 2; ++t2) {
        const int col = colbase + (ct << 5) + (t2 << 4) + l15;
        const float* p = Wh2h + (size_t)col * 512 + kb0 + c * 32;
        f32x4 w0 = *(const f32x4*)p;
        f32x4 w1 = *(const f32x4*)(p + 4);
        short8 hi8, lo8;
#pragma unroll
        for (int e = 0; e < 4; ++e) {
          unsigned short h = f2bf(w0[e]);
          hi8[e] = (short)h;
          lo8[e] = (short)f2bf(w0[e] - bf2f(h));
        }
#pragma unroll
        for (int e = 0; e < 4; ++e) {
          unsigned short h = f2bf(w1[e]);
          hi8[4 + e] = (short)h;
          lo8[4 + e] = (short)f2bf(w1[e] - bf2f(h));
        }
        Whi[c][t2] = hi8;
        Wlo[c][t2] = lo8;
      }
    }
  }

  // ---- xb = x@Wx2h.T + b_x2h + b_h2h  (fp32 VALU, once) ----
  {
    const int r = tid >> 4, ci = tid & 15;
    float* xs = (float*)(smem + XS_OFF);
    const float* xp = x + (size_t)(rowbase + r) * 128 + ci * 8;
    f32x4 v0 = *(const f32x4*)xp;
    f32x4 v1 = *(const f32x4*)(xp + 4);
    *(f32x4*)&xs[r * 132 + ci * 8] = v0;
    *(f32x4*)&xs[r * 132 + ci * 8 + 4] = v1;
  }
  __syncthreads();
  {
    const int r = tid >> 4, c4 = (tid & 15) << 2;
    const int jg = colbase + c4;
    f32x4 acc = *(const f32x4*)&bx2h[jg];
    acc += *(const f32x4*)&bh2h[jg];
    const float* xs = (const float*)(smem + XS_OFF);
#pragma unroll 2
    for (int k = 0; k < 128; k += 4) {
      f32x4 xv = *(const f32x4*)&xs[r * 132 + k];
#pragma unroll
      for (int jj = 0; jj < 4; ++jj) {
        f32x4 wvv = *(const f32x4*)(Wx2h + (size_t)(jg + jj) * 128 + k);
        acc[jj] += xv[0] * wvv[0] + xv[1] * wvv[1] + xv[2] * wvv[2] + xv[3] * wvv[3];
      }
    }
    float* xbl = (float*)(smem + XB_OFF);
    *(f32x4*)&xbl[r * 68 + c4] = acc;
  }
  __syncthreads();

  // kh==0 waves keep xb as C-init fragments (C layout: col=l&15, row=lq*4+j)
  f32x4 xbf0 = {0, 0, 0, 0}, xbf1 = {0, 0, 0, 0};
  if (kh == 0) {
    const float* xbl = (const float*)(smem + XB_OFF);
#pragma unroll
    for (int j = 0; j < 4; ++j) {
      xbf0[j] = xbl[(lq * 4 + j) * 68 + (ct << 5) + l15];
      xbf1[j] = xbl[(lq * 4 + j) * 68 + (ct << 5) + 16 + l15];
    }
  }

  // store h (relu applied) as packed (hi | lo<<16) agent-coherent dwords
  auto store_h = [&](unsigned* buf, f32x4 s0, f32x4 s1) {
    const int cg = (cb << 1) + ct;  // global k-chunk this wave's cols map to
    unsigned* chb = buf + ((size_t)(g * 16 + cg) << 9);  // 512 dw per chunk
    const int e = l & 7;
#pragma unroll
    for (int t2 = 0; t2 < 2; ++t2) {
      f32x4 sv = t2 ? s1 : s0;
      const int koff = (t2 << 4) + l15;       // 0..31 within chunk
      const int lcb = ((koff >> 3) << 4);     // consumer lane base
#pragma unroll
      for (int j = 0; j < 4; ++j) {
        float v = sv[j];
        v = v > 0.f ? v : 0.f;
        unsigned short hi = f2bf(v);
        unsigned short lo = f2bf(v - bf2f(hi));
        const int lane = lcb + (lq << 2) + j;
        __hip_atomic_store(chb + (e << 6) + lane,
                           (unsigned)hi | ((unsigned)lo << 16),
                           __ATOMIC_RELAXED, __HIP_MEMORY_SCOPE_AGENT);
      }
    }
  };

  // Sync: __syncthreads drains vmcnt (coherent stores acked at MALL) before
  // tid0 signals. No cache-maintenance instructions anywhere.
  auto sync_step = [&](int t) {
    __syncthreads();
    if (tid == 0) {
      atomicAdd(ctr_g, 1);  // device-scope signal
      const int target = 8 * (t + 1);
      while (__hip_atomic_load(ctr_g, __ATOMIC_RELAXED,
                               __HIP_MEMORY_SCOPE_AGENT) < target)
        __builtin_amdgcn_s_sleep(1);
    }
    __syncthreads();
  };

  // ---- t=0: h = relu(xb) ----
  if (kh == 0) store_h(hbuf0, xbf0, xbf1);
  sync_step(0);

  // ---- 127 recurrence steps ----
  for (int t = 1; t < 128; ++t) {
    const unsigned* hbase = ((t & 1) ? hbuf0 : hbuf1) +
                            ((size_t)(g * 16 + kh * 8) << 9);
    // issue ALL 64 coherent loads up front (one latency exposure)
    unsigned w[64];
#pragma unroll
    for (int c = 0; c < 8; ++c)
#pragma unroll
      for (int e = 0; e < 8; ++e)
        w[c * 8 + e] = __hip_atomic_load(hbase + (c << 9) + (e << 6) + l,
                                         __ATOMIC_RELAXED,
                                         __HIP_MEMORY_SCOPE_AGENT);
    f32x4 a0, a1, b0, b1;
    if (kh == 0) {
      a0 = xbf0; a1 = xbf1;
    } else {
      a0 = (f32x4){0, 0, 0, 0}; a1 = a0;
    }
    b0 = (f32x4){0, 0, 0, 0}; b1 = b0;
#pragma unroll
    for (int c = 0; c < 8; ++c) {
      short8 ahi, alo;
#pragma unroll
      for (int e = 0; e < 8; ++e) {
        unsigned wv = w[c * 8 + e];
        ahi[e] = (short)(wv & 0xFFFFu);
        alo[e] = (short)(wv >> 16);
      }
      if ((c & 1) == 0) {
        a0 = __builtin_amdgcn_mfma_f32_16x16x32_bf16(ahi, Whi[c][0], a0, 0, 0, 0);
        a0 = __builtin_amdgcn_mfma_f32_16x16x32_bf16(alo, Whi[c][0], a0, 0, 0, 0);
        a0 = __builtin_amdgcn_mfma_f32_16x16x32_bf16(ahi, Wlo[c][0], a0, 0, 0, 0);
        a1 = __builtin_amdgcn_mfma_f32_16x16x32_bf16(ahi, Whi[c][1], a1, 0, 0, 0);
        a1 = __builtin_amdgcn_mfma_f32_16x16x32_bf16(alo, Whi[c][1], a1, 0, 0, 0);
        a1 = __builtin_amdgcn_mfma_f32_16x16x32_bf16(ahi, Wlo[c][1], a1, 0, 0, 0);
      } else {
        b0 = __builtin_amdgcn_mfma_f32_16x16x32_bf16(ahi, Whi[c][0], b0, 0, 0, 0);
        b0 = __builtin_amdgcn_mfma_f32_16x16x32_bf16(alo, Whi[c][0], b0, 0, 0, 0);
        b0 = __builtin_amdgcn_mfma_f32_16x16x32_bf16(ahi, Wlo[c][0], b0, 0, 0, 0);
        b1 = __builtin_amdgcn_mfma_f32_16x16x32_bf16(ahi, Whi[c][1], b1, 0, 0, 0);
        b1 = __builtin_amdgcn_mfma_f32_16x16x32_bf16(alo, Whi[c][1], b1, 0, 0, 0);
        b1 = __builtin_amdgcn_mfma_f32_16x16x32_bf16(ahi, Wlo[c][1], b1, 0, 0, 0);
      }
    }
    f32x4 s0 = a0 + b0, s1 = a1 + b1;
    float* red = (float*)(smem + RED_OFF);
    if (kh == 1) {  // write K-half partials for the kh==0 partner wave
#pragma unroll
      for (int t2 = 0; t2 < 2; ++t2)
#pragma unroll
        for (int j = 0; j < 4; ++j)
          red[(ct * 16 + lq * 4 + j) * 36 + t2 * 16 + l15] = t2 ? s1[j] : s0[j];
    }
    __syncthreads();
    if (kh == 0) {
#pragma unroll
      for (int t2 = 0; t2 < 2; ++t2)
#pragma unroll
        for (int j = 0; j < 4; ++j) {
          float rv = red[(ct * 16 + lq * 4 + j) * 36 + t2 * 16 + l15];
          if (t2) s1[j] += rv; else s0[j] += rv;
        }
      store_h((t & 1) ? hbuf1 : hbuf0, s0, s1);
    }
    sync_step(t);
  }

  // ---- epilogue: out = h@Wh2y.T + b_h2y (fp32 VALU via LDS) ----
  {  // reconstruct final h (hbuf1, packed dwords) -> h_f32[16][520]
    const int r = tid >> 4, cgi = tid & 15;
    float* hf = (float*)(smem + HF_OFF);
    const unsigned* hb = hbuf1 + ((size_t)(g * 16 + cgi) << 9);
#pragma unroll
    for (int lg = 0; lg < 4; ++lg) {
      const int ln = lg * 16 + r;
      f32x4 v0, v1;
#pragma unroll
      for (int e = 0; e < 4; ++e) {
        unsigned wv = __hip_atomic_load(hb + (e << 6) + ln, __ATOMIC_RELAXED,
                                        __HIP_MEMORY_SCOPE_AGENT);
        v0[e] = bf2f((unsigned short)(wv & 0xFFFFu)) +
                bf2f((unsigned short)(wv >> 16));
      }
#pragma unroll
      for (int e = 0; e < 4; ++e) {
        unsigned wv = __hip_atomic_load(hb + ((e + 4) << 6) + ln,
                                        __ATOMIC_RELAXED,
                                        __HIP_MEMORY_SCOPE_AGENT);
        v1[e] = bf2f((unsigned short)(wv & 0xFFFFu)) +
                bf2f((unsigned short)(wv >> 16));
      }
      *(f32x4*)&hf[r * 520 + cgi * 32 + lg * 8] = v0;
      *(f32x4*)&hf[r * 520 + cgi * 32 + lg * 8 + 4] = v1;
    }
  }
  {  // stage Wh2y slice [32][522]
    float* wl = (float*)(smem + WL_OFF);
    const int wr = tid >> 3, seg = tid & 7;
    const int ocb = cb << 5;
    const float* wp = Wh2y + (size_t)(ocb + wr) * 512;
#pragma unroll 8
    for (int i = 0; i < 32; ++i) {
      const int c = (seg + i * 8) << 1;
      *(f32x2*)&wl[wr * 522 + c] = *(const f32x2*)&wp[c];
    }
  }
  __syncthreads();
  {
    const int r = tid >> 4, c2 = (tid & 15) << 1;
    const int ocb = cb << 5;
    const float* hf = (const float*)(smem + HF_OFF);
    const float* wl = (const float*)(smem + WL_OFF);
    float acc0 = 0.f, acc1 = 0.f;
#pragma unroll 8
    for (int k = 0; k < 512; k += 2) {
      f32x2 hv = *(const f32x2*)&hf[r * 520 + k];
      f32x2 w0 = *(const f32x2*)&wl[c2 * 522 + k];
      f32x2 w1 = *(const f32x2*)&wl[(c2 + 1) * 522 + k];
      acc0 += hv[0] * w0[0] + hv[1] * w0[1];
      acc1 += hv[0] * w1[0] + hv[1] * w1[1];
    }
    acc0 += bh2y[ocb + c2];
    acc1 += bh2y[ocb + c2 + 1];
    f32x2 o; o[0] = acc0; o[1] = acc1;
    *(f32x2*)&out[(size_t)(rowbase + r) * 256 + ocb + c2] = o;
  }
}

extern "C" void kernel_launch(void* const* d_in, const int* in_sizes, int n_in,
                              void* d_out, int out_size, void* d_ws,
                              size_t ws_size, hipStream_t stream) {
  const float* x    = (const float*)d_in[0];
  const float* Wx2h = (const float*)d_in[1];
  const float* bx2h = (const float*)d_in[2];
  const float* Wh2h = (const float*)d_in[3];
  const float* bh2h = (const float*)d_in[4];
  const float* Wh2y = (const float*)d_in[5];
  const float* bh2y = (const float*)d_in[6];
  // zero the 32 per-group arrival counters (256B apart; ws re-poisoned each call)
  (void)hipMemsetAsync((char*)d_ws + CTR_OFF, 0, 32 * CTR_STRIDE * 4, stream);
  (void)hipFuncSetAttribute((const void*)recnet_kernel,
                            hipFuncAttributeMaxDynamicSharedMemorySize,
                            LDS_BYTES);
  recnet_kernel<<<dim3(256), dim3(256), LDS_BYTES, stream>>>(
      x, Wx2h, bx2h, Wh2h, bh2h, Wh2y, bh2y, (float*)d_out, (char*)d_ws);
}

// Round 7
// 340.421 us; speedup vs baseline: 12.3468x; 1.5504x over previous
//
#include <hip/hip_runtime.h>

// RecNet: xh = x@Wx2h.T + b_x2h (once); 128x: h = relu(xh + h@Wh2h.T + b_h2h);
//         out = h@Wh2y.T + b_h2y.
// 32 row-groups (16 batch rows) x 8 col-WGs (64 hidden cols); Wh2h register-
// resident as bf16 hi/lo MFMA fragments (3-product fp32 emulation).
// R5 lesson: all-MALL h exchange = 613MB/dispatch, 3.7us/step. Since bids
// {g, g+32, ...} are all congruent mod 8, each group's 8 WGs share an XCD
// under round-robin dispatch -> adaptive fast path keeps h in the shared
// XCD L2 (plain stores/loads + per-step L1-only buffer_inv sc0). Uniformity
// is CHECKED at runtime via HW_REG_XCC_ID; non-uniform groups fall back to
// the proven agent-scope atomic path (G16-safe either way). Signal stays
// agent-scope: consumer seeing signal => producer stores drained to L2/MALL.
// 102KB dynamic LDS forces 1 WG/CU -> all 256 WGs co-resident (spin-safe).

typedef __attribute__((ext_vector_type(8))) short short8;
typedef __attribute__((ext_vector_type(4))) float f32x4;
typedef __attribute__((ext_vector_type(2))) float f32x2;
typedef __attribute__((ext_vector_type(4))) unsigned uint4v;

#define LDS_BYTES 102400
#define XS_OFF 0        // x stage   [16][132] f32 = 8448 B
#define XB_OFF 8448     // xb        [16][68]  f32 = 4352 B
#define RED_OFF 12800   // reduction [2][16][36] f32 = 4608 B
#define FLAG_OFF 17408  // fast-path flag (int)
#define HF_OFF 0        // epilogue h_f32 [16][520] f32 = 33280 B
#define WL_OFF 33280    // epilogue Wlds  [32][522] f32 = 66816 B

// h buffer layout (per group, per chunk of 32 hidden units):
//   element (row ri 0..15, k_local kk 0..31) -> dword idx = lane*8 + e where
//   lane = (kk>>3)*16 + ri, e = kk&7  (consumer A-frag loads are 2x dwordx4).
#define HBUF_BYTES (1u << 20)
#define CTR_OFF (2u << 20)
#define CTR2_OFF (CTR_OFF + 8192)
#define XCD_OFF (CTR_OFF + 16384)
#define CTR_STRIDE 64  // ints; 256B per group counter line

__device__ __forceinline__ unsigned short f2bf(float f) {
  unsigned u = __builtin_bit_cast(unsigned, f);
  u += 0x7FFFu + ((u >> 16) & 1u);  // RNE (inputs finite)
  return (unsigned short)(u >> 16);
}
__device__ __forceinline__ float bf2f(unsigned short h) {
  unsigned u = ((unsigned)h) << 16;
  return __builtin_bit_cast(float, u);
}
__device__ __forceinline__ float unpk(unsigned v) {
  return bf2f((unsigned short)(v & 0xFFFFu)) + bf2f((unsigned short)(v >> 16));
}

extern "C" __global__ void __launch_bounds__(256, 1)
recnet_kernel(const float* __restrict__ x, const float* __restrict__ Wx2h,
              const float* __restrict__ bx2h, const float* __restrict__ Wh2h,
              const float* __restrict__ bh2h, const float* __restrict__ Wh2y,
              const float* __restrict__ bh2y, float* __restrict__ out,
              char* __restrict__ ws) {
  extern __shared__ char smem[];
  const int tid = threadIdx.x;
  const int l   = tid & 63;
  const int wv  = tid >> 6;
  const int ct  = wv & 1;   // col-half of this WG's 64 cols
  const int kh  = wv >> 1;  // K-half (0: k<256 + xb, 1: k>=256)
  const int bid = blockIdx.x;
  const int g   = bid & 31;  // row-group (all its bids congruent mod 8)
  const int cb  = bid >> 5;  // col-block 0..7
  const int rowbase = g << 4;
  const int colbase = cb << 6;
  const int l15 = l & 15;
  const int lq  = l >> 4;

  unsigned* hbuf0 = (unsigned*)ws;
  unsigned* hbuf1 = (unsigned*)(ws + HBUF_BYTES);
  int* ctr_g  = (int*)(ws + CTR_OFF)  + g * CTR_STRIDE;
  int* ctr2_g = (int*)(ws + CTR2_OFF) + g * CTR_STRIDE;
  int* xcds   = (int*)(ws + XCD_OFF);

  // ---- XCD-uniformity check (once; decides fast L2 path vs MALL path) ----
  if (tid == 0) {
    unsigned xcc;
    asm volatile("s_getreg_b32 %0, hwreg(HW_REG_XCC_ID)" : "=s"(xcc));
    __hip_atomic_store(&xcds[g * 8 + cb], (int)(xcc & 0xFFu) | 0x100,
                       __ATOMIC_RELAXED, __HIP_MEMORY_SCOPE_AGENT);
    asm volatile("s_waitcnt vmcnt(0)" ::: "memory");  // store acked pre-signal
    __hip_atomic_fetch_add(ctr2_g, 1, __ATOMIC_RELAXED,
                           __HIP_MEMORY_SCOPE_AGENT);
    while (__hip_atomic_load(ctr2_g, __ATOMIC_RELAXED,
                             __HIP_MEMORY_SCOPE_AGENT) < 8)
      __builtin_amdgcn_s_sleep(1);
    asm volatile("" ::: "memory");
    int x0 = __hip_atomic_load(&xcds[g * 8], __ATOMIC_RELAXED,
                               __HIP_MEMORY_SCOPE_AGENT);
    int uni = 1;
    for (int i = 1; i < 8; ++i)
      uni &= (__hip_atomic_load(&xcds[g * 8 + i], __ATOMIC_RELAXED,
                                __HIP_MEMORY_SCOPE_AGENT) == x0);
    *(int*)(smem + FLAG_OFF) = uni;
  }
  __syncthreads();
  const bool fast = *(const int*)(smem + FLAG_OFF) != 0;

  // ---- Wh2h fragment preload: bf16 hi/lo, register resident (128 VGPR) ----
  // B-frag: lane holds col=l&15, k = kb0 + chunk*32 + (l>>4)*8 + e. Same
  // k-placement as A -> invariant to any intra-lane k permutation.
  short8 Whi[8][2], Wlo[8][2];
  {
    const int kb0 = (kh << 8) + (lq << 3);
#pragma unroll
    for (int c = 0; c < 8; ++c) {
#pragma unroll
      for (int t2 = 0; t2 < 2; ++t2) {
        const int col = colbase + (ct << 5) + (t2 << 4) + l15;
        const float* p = Wh2h + (size_t)col * 512 + kb0 + c * 32;
        f32x4 w0 = *(const f32x4*)p;
        f32x4 w1 = *(const f32x4*)(p + 4);
        short8 hi8, lo8;
#pragma unroll
        for (int e = 0; e < 4; ++e) {
          unsigned short h = f2bf(w0[e]);
          hi8[e] = (short)h;
          lo8[e] = (short)f2bf(w0[e] - bf2f(h));
        }
#pragma unroll
        for (int e = 0; e < 4; ++e) {
          unsigned short h = f2bf(w1[e]);
          hi8[4 + e] = (short)h;
          lo8[4 + e] = (short)f2bf(w1[e] - bf2f(h));
        }
        Whi[c][t2] = hi8;
        Wlo[c][t2] = lo8;
      }
    }
  }

  // ---- xb = x@Wx2h.T + b_x2h + b_h2h  (fp32 VALU, once) ----
  {
    const int r = tid >> 4, ci = tid & 15;
    float* xs = (float*)(smem + XS_OFF);
    const float* xp = x + (size_t)(rowbase + r) * 128 + ci * 8;
    *(f32x4*)&xs[r * 132 + ci * 8] = *(const f32x4*)xp;
    *(f32x4*)&xs[r * 132 + ci * 8 + 4] = *(const f32x4*)(xp + 4);
  }
  __syncthreads();
  {
    const int r = tid >> 4, c4 = (tid & 15) << 2;
    const int jg = colbase + c4;
    f32x4 acc = *(const f32x4*)&bx2h[jg];
    acc += *(const f32x4*)&bh2h[jg];
    const float* xs = (const float*)(smem + XS_OFF);
#pragma unroll 2
    for (int k = 0; k < 128; k += 4) {
      f32x4 xv = *(const f32x4*)&xs[r * 132 + k];
#pragma unroll
      for (int jj = 0; jj < 4; ++jj) {
        f32x4 wvv = *(const f32x4*)(Wx2h + (size_t)(jg + jj) * 128 + k);
        acc[jj] += xv[0] * wvv[0] + xv[1] * wvv[1] + xv[2] * wvv[2] + xv[3] * wvv[3];
      }
    }
    float* xbl = (float*)(smem + XB_OFF);
    *(f32x4*)&xbl[r * 68 + c4] = acc;
  }
  __syncthreads();

  // kh==0 waves keep xb as C-init fragments (C layout: col=l&15, row=lq*4+j)
  f32x4 xbf0 = {0, 0, 0, 0}, xbf1 = {0, 0, 0, 0};
  if (kh == 0) {
    const float* xbl = (const float*)(smem + XB_OFF);
#pragma unroll
    for (int j = 0; j < 4; ++j) {
      xbf0[j] = xbl[(lq * 4 + j) * 68 + (ct << 5) + l15];
      xbf1[j] = xbl[(lq * 4 + j) * 68 + (ct << 5) + 16 + l15];
    }
  }

  // store h (relu) as packed (hi|lo<<16) dwords; fast = plain (lands in the
  // shared XCD L2), slow = agent atomics (MALL). idx derivation in header.
  auto store_h = [&](unsigned* buf, f32x4 s0, f32x4 s1) {
    const int cg = (cb << 1) + ct;
    unsigned* chb = buf + ((size_t)(g * 16 + cg) << 9);
#pragma unroll
    for (int t2 = 0; t2 < 2; ++t2) {
      f32x4 sv = t2 ? s1 : s0;
      const int blk = (t2 << 1) + (l15 >> 3);  // koff>>3
#pragma unroll
      for (int j = 0; j < 4; ++j) {
        float v = sv[j];
        v = v > 0.f ? v : 0.f;
        unsigned short hi = f2bf(v);
        unsigned short lo = f2bf(v - bf2f(hi));
        unsigned pk = (unsigned)hi | ((unsigned)lo << 16);
        const int idx = blk * 128 + ((lq << 2) + j) * 8 + (l & 7);
        if (fast) chb[idx] = pk;
        else __hip_atomic_store(chb + idx, pk, __ATOMIC_RELAXED,
                                __HIP_MEMORY_SCOPE_AGENT);
      }
    }
  };

  // __syncthreads drains vmcnt (stores in shared L2 / MALL) before signal.
  auto sync_step = [&](int t) {
    __syncthreads();
    if (tid == 0) {
      atomicAdd(ctr_g, 1);  // agent-scope signal
      const int target = 8 * (t + 1);
      while (__hip_atomic_load(ctr_g, __ATOMIC_RELAXED,
                               __HIP_MEMORY_SCOPE_AGENT) < target)
        __builtin_amdgcn_s_sleep(1);
    }
    __syncthreads();
    if (fast)  // L1-only invalidate so plain loads refill from shared L2
      asm volatile("buffer_inv sc0\n\ts_waitcnt vmcnt(0)" ::: "memory");
  };

  // ---- t=0: h = relu(xb) ----
  if (kh == 0) store_h(hbuf0, xbf0, xbf1);
  sync_step(0);

  // ---- 127 recurrence steps ----
  for (int t = 1; t < 128; ++t) {
    const unsigned* hbase = ((t & 1) ? hbuf0 : hbuf1) +
                            ((size_t)(g * 16 + kh * 8) << 9);
    unsigned w[64];
    if (fast) {
#pragma unroll
      for (int c = 0; c < 8; ++c) {
        uint4v q0 = *(const uint4v*)(hbase + (c << 9) + l * 8);
        uint4v q1 = *(const uint4v*)(hbase + (c << 9) + l * 8 + 4);
#pragma unroll
        for (int i = 0; i < 4; ++i) {
          w[c * 8 + i] = q0[i];
          w[c * 8 + 4 + i] = q1[i];
        }
      }
    } else {
#pragma unroll
      for (int c = 0; c < 8; ++c)
#pragma unroll
        for (int e = 0; e < 8; ++e)
          w[c * 8 + e] = __hip_atomic_load(hbase + (c << 9) + l * 8 + e,
                                           __ATOMIC_RELAXED,
                                           __HIP_MEMORY_SCOPE_AGENT);
    }
    f32x4 a0, a1, b0, b1;
    if (kh == 0) {
      a0 = xbf0; a1 = xbf1;
    } else {
      a0 = (f32x4){0, 0, 0, 0}; a1 = a0;
    }
    b0 = (f32x4){0, 0, 0, 0}; b1 = b0;
#pragma unroll
    for (int c = 0; c < 8; ++c) {
      short8 ahi, alo;
#pragma unroll
      for (int e = 0; e < 8; ++e) {
        unsigned wv2 = w[c * 8 + e];
        ahi[e] = (short)(wv2 & 0xFFFFu);
        alo[e] = (short)(wv2 >> 16);
      }
      if ((c & 1) == 0) {
        a0 = __builtin_amdgcn_mfma_f32_16x16x32_bf16(ahi, Whi[c][0], a0, 0, 0, 0);
        a0 = __builtin_amdgcn_mfma_f32_16x16x32_bf16(alo, Whi[c][0], a0, 0, 0, 0);
        a0 = __builtin_amdgcn_mfma_f32_16x16x32_bf16(ahi, Wlo[c][0], a0, 0, 0, 0);
        a1 = __builtin_amdgcn_mfma_f32_16x16x32_bf16(ahi, Whi[c][1], a1, 0, 0, 0);
        a1 = __builtin_amdgcn_mfma_f32_16x16x32_bf16(alo, Whi[c][1], a1, 0, 0, 0);
        a1 = __builtin_amdgcn_mfma_f32_16x16x32_bf16(ahi, Wlo[c][1], a1, 0, 0, 0);
      } else {
        b0 = __builtin_amdgcn_mfma_f32_16x16x32_bf16(ahi, Whi[c][0], b0, 0, 0, 0);
        b0 = __builtin_amdgcn_mfma_f32_16x16x32_bf16(alo, Whi[c][0], b0, 0, 0, 0);
        b0 = __builtin_amdgcn_mfma_f32_16x16x32_bf16(ahi, Wlo[c][0], b0, 0, 0, 0);
        b1 = __builtin_amdgcn_mfma_f32_16x16x32_bf16(ahi, Whi[c][1], b1, 0, 0, 0);
        b1 = __builtin_amdgcn_mfma_f32_16x16x32_bf16(alo, Whi[c][1], b1, 0, 0, 0);
        b1 = __builtin_amdgcn_mfma_f32_16x16x32_bf16(ahi, Wlo[c][1], b1, 0, 0, 0);
      }
    }
    f32x4 s0 = a0 + b0, s1 = a1 + b1;
    float* red = (float*)(smem + RED_OFF);
    if (kh == 1) {  // write K-half partials for the kh==0 partner wave
#pragma unroll
      for (int t2 = 0; t2 < 2; ++t2)
#pragma unroll
        for (int j = 0; j < 4; ++j)
          red[(ct * 16 + lq * 4 + j) * 36 + t2 * 16 + l15] = t2 ? s1[j] : s0[j];
    }
    __syncthreads();
    if (kh == 0) {
#pragma unroll
      for (int t2 = 0; t2 < 2; ++t2)
#pragma unroll
        for (int j = 0; j < 4; ++j) {
          float rv = red[(ct * 16 + lq * 4 + j) * 36 + t2 * 16 + l15];
          if (t2) s1[j] += rv; else s0[j] += rv;
        }
      store_h((t & 1) ? hbuf1 : hbuf0, s0, s1);
    }
    sync_step(t);
  }

  // ---- epilogue: out = h@Wh2y.T + b_h2y (fp32 VALU via LDS) ----
  {  // reconstruct final h (hbuf1) -> h_f32[16][520]
    const int r = tid >> 4, cgi = tid & 15;
    float* hf = (float*)(smem + HF_OFF);
    const unsigned* hb = hbuf1 + ((size_t)(g * 16 + cgi) << 9);
#pragma unroll
    for (int b = 0; b < 4; ++b) {
      float* dst = &hf[r * 520 + cgi * 32 + b * 8];
      if (fast) {
        uint4v q0 = *(const uint4v*)(hb + b * 128 + r * 8);
        uint4v q1 = *(const uint4v*)(hb + b * 128 + r * 8 + 4);
#pragma unroll
        for (int i = 0; i < 4; ++i) {
          dst[i] = unpk(q0[i]);
          dst[4 + i] = unpk(q1[i]);
        }
      } else {
#pragma unroll
        for (int i = 0; i < 8; ++i)
          dst[i] = unpk(__hip_atomic_load(hb + b * 128 + r * 8 + i,
                                          __ATOMIC_RELAXED,
                                          __HIP_MEMORY_SCOPE_AGENT));
      }
    }
  }
  {  // stage Wh2y slice [32][522]
    float* wl = (float*)(smem + WL_OFF);
    const int wr = tid >> 3, seg = tid & 7;
    const int ocb = cb << 5;
    const float* wp = Wh2y + (size_t)(ocb + wr) * 512;
#pragma unroll 8
    for (int i = 0; i < 32; ++i) {
      const int c = (seg + i * 8) << 1;
      *(f32x2*)&wl[wr * 522 + c] = *(const f32x2*)&wp[c];
    }
  }
  __syncthreads();
  {
    const int r = tid >> 4, c2 = (tid & 15) << 1;
    const int ocb = cb << 5;
    const float* hf = (const float*)(smem + HF_OFF);
    const float* wl = (const float*)(smem + WL_OFF);
    float acc0 = 0.f, acc1 = 0.f;
#pragma unroll 8
    for (int k = 0; k < 512; k += 2) {
      f32x2 hv = *(const f32x2*)&hf[r * 520 + k];
      f32x2 w0 = *(const f32x2*)&wl[c2 * 522 + k];
      f32x2 w1 = *(const f32x2*)&wl[(c2 + 1) * 522 + k];
      acc0 += hv[0] * w0[0] + hv[1] * w0[1];
      acc1 += hv[0] * w1[0] + hv[1] * w1[1];
    }
    acc0 += bh2y[ocb + c2];
    acc1 += bh2y[ocb + c2 + 1];
    f32x2 o; o[0] = acc0; o[1] = acc1;
    *(f32x2*)&out[(size_t)(rowbase + r) * 256 + ocb + c2] = o;
  }
}

extern "C" void kernel_launch(void* const* d_in, const int* in_sizes, int n_in,
                              void* d_out, int out_size, void* d_ws,
                              size_t ws_size, hipStream_t stream) {
  const float* x    = (const float*)d_in[0];
  const float* Wx2h = (const float*)d_in[1];
  const float* bx2h = (const float*)d_in[2];
  const float* Wh2h = (const float*)d_in[3];
  const float* bh2h = (const float*)d_in[4];
  const float* Wh2y = (const float*)d_in[5];
  const float* bh2y = (const float*)d_in[6];
  // zero the step + startup counters (ws re-poisoned to 0xAA each call)
  (void)hipMemsetAsync((char*)d_ws + CTR_OFF, 0, 16384, stream);
  (void)hipFuncSetAttribute((const void*)recnet_kernel,
                            hipFuncAttributeMaxDynamicSharedMemorySize,
                            LDS_BYTES);
  recnet_kernel<<<dim3(256), dim3(256), LDS_BYTES, stream>>>(
      x, Wx2h, bx2h, Wh2h, bh2h, Wh2y, bh2y, (float*)d_out, (char*)d_ws);
}